// Round 1
// baseline (1995.320 us; speedup 1.0000x reference)
//
#include <hip/hip_runtime.h>
#include <hip/hip_bf16.h>

#define NN 50000
#define NE 800000
#define HD 256
#define KIN 128

typedef __attribute__((ext_vector_type(8))) short bf16x8;
typedef __attribute__((ext_vector_type(4))) float f32x4;

static __device__ __forceinline__ short f2b(float f){
  union { __hip_bfloat16 h; short s; } u;
  u.h = __float2bfloat16(f);
  return u.s;
}
static __device__ __forceinline__ float b2f(short s){
  union { __hip_bfloat16 h; short s; } u;
  u.s = s;
  return __bfloat162float(u.h);
}
// softplus(x) - log(2)
static __device__ __forceinline__ float sspf(float x){
  return fmaxf(x, 0.0f) + log1pf(expf(-fabsf(x))) - 0.69314718055994531f;
}
static __device__ __forceinline__ bf16x8 load_a_f32(const float* __restrict__ p){
  const float4 x0 = *reinterpret_cast<const float4*>(p);
  const float4 x1 = *reinterpret_cast<const float4*>(p + 4);
  bf16x8 t;
  t[0]=f2b(x0.x); t[1]=f2b(x0.y); t[2]=f2b(x0.z); t[3]=f2b(x0.w);
  t[4]=f2b(x1.x); t[5]=f2b(x1.y); t[6]=f2b(x1.z); t[7]=f2b(x1.w);
  return t;
}

// ---------- weight fp32 -> bf16 ----------
__global__ void k_convert(const float* __restrict__ wfc, const float* __restrict__ we1,
                          const float* __restrict__ we2,
                          short* __restrict__ wfcb, short* __restrict__ we1b,
                          short* __restrict__ we2b){
  const int i = blockIdx.x*256 + threadIdx.x;
  if (i < HD*KIN) wfcb[i] = f2b(wfc[i]);
  if (i < 32*KIN) we1b[i] = f2b(we1[i]);
  if (i < HD*32)  we2b[i] = f2b(we2[i]);
}

// ---------- feat = nfeat @ W_fc^T  (+ el, er) ----------
// block = 256 thr (4 waves); block tile = 64 nodes x 256 cols; wave w owns cols [w*64, w*64+64)
__global__ __launch_bounds__(256) void k_feat(
    const float* __restrict__ nfeat, const short* __restrict__ wfcb,
    const float* __restrict__ attn_l, const float* __restrict__ attn_r,
    short* __restrict__ featb, float* __restrict__ el, float* __restrict__ er)
{
  const int n0 = blockIdx.x * 64;
  const int tid = threadIdx.x;
  const int w = tid >> 6, l = tid & 63, l15 = l & 15, lq = l >> 4;

  f32x4 acc[4][4];
#pragma unroll
  for (int a=0;a<4;++a)
#pragma unroll
    for (int b=0;b<4;++b) acc[a][b] = (f32x4)0.0f;

#pragma unroll
  for (int ks=0; ks<4; ++ks){
    const int k0 = ks*32 + lq*8;
    bf16x8 af[4];
#pragma unroll
    for (int tr=0; tr<4; ++tr){
      int row = n0 + tr*16 + l15;
      if (row >= NN) row = NN-1;
      af[tr] = load_a_f32(nfeat + row*KIN + k0);
    }
#pragma unroll
    for (int tc=0; tc<4; ++tc){
      const int c = w*64 + tc*16 + l15;
      const bf16x8 bfrag = *reinterpret_cast<const bf16x8*>(wfcb + c*KIN + k0);
#pragma unroll
      for (int tr=0; tr<4; ++tr)
        acc[tr][tc] = __builtin_amdgcn_mfma_f32_16x16x32_bf16(af[tr], bfrag, acc[tr][tc], 0,0,0);
    }
  }

  float alr[4], arr_[4];
#pragma unroll
  for (int tc=0;tc<4;++tc){
    const int c = w*64 + tc*16 + l15;
    alr[tc] = attn_l[c]; arr_[tc] = attn_r[c];
  }
  float pl[4][4][2], pr[4][4][2];
#pragma unroll
  for (int tr=0;tr<4;++tr)
#pragma unroll
    for (int j=0;j<4;++j){ pl[tr][j][0]=pl[tr][j][1]=0.f; pr[tr][j][0]=pr[tr][j][1]=0.f; }

  // D layout: row = tr*16 + lq*4 + j (node), col = w*64 + tc*16 + l15
#pragma unroll
  for (int tr=0;tr<4;++tr){
    const int rowb = tr*16 + lq*4;
#pragma unroll
    for (int tc=0;tc<4;++tc){
      const int c = w*64 + tc*16 + l15;
      const int h2 = tc>>1;
#pragma unroll
      for (int j=0;j<4;++j){
        const float v = acc[tr][tc][j];
        const int node = n0 + rowb + j;
        if (node < NN) featb[node*HD + c] = f2b(v);
        pl[tr][j][h2] += v*alr[tc];
        pr[tr][j][h2] += v*arr_[tc];
      }
    }
  }
  // reduce over the 16 lanes sharing lq (sum over cols within head)
#pragma unroll
  for (int m=1;m<16;m<<=1){
#pragma unroll
    for (int tr=0;tr<4;++tr)
#pragma unroll
      for (int j=0;j<4;++j){
        pl[tr][j][0] += __shfl_xor(pl[tr][j][0], m, 64);
        pl[tr][j][1] += __shfl_xor(pl[tr][j][1], m, 64);
        pr[tr][j][0] += __shfl_xor(pr[tr][j][0], m, 64);
        pr[tr][j][1] += __shfl_xor(pr[tr][j][1], m, 64);
      }
  }
#pragma unroll
  for (int tr=0;tr<4;++tr)
#pragma unroll
    for (int j=0;j<4;++j)
      if (l15 == tr*4+j){
        const int node = n0 + tr*16 + lq*4 + j;
        if (node < NN){
          el[node*8 + 2*w + 0] = pl[tr][j][0];
          el[node*8 + 2*w + 1] = pl[tr][j][1];
          er[node*8 + 2*w + 0] = pr[tr][j][0];
          er[node*8 + 2*w + 1] = pr[tr][j][1];
        }
      }
}

// ---------- fused edge MLP -> ee, e ----------
// block = 256 thr, 64 edges. GEMM1: [64,128]x[128,32] (wave w = rows w*16..+15);
// ssp -> X (LDS, bf16, padded 40-short rows); GEMM2: [64,32]x[32,256] (wave w = cols w*64..+63)
__global__ __launch_bounds__(256) void k_edge(
    const float* __restrict__ efeat, const float* __restrict__ rij,
    const int* __restrict__ src, const int* __restrict__ dst,
    const short* __restrict__ we1b, const float* __restrict__ be1,
    const short* __restrict__ we2b, const float* __restrict__ be2,
    const float* __restrict__ attn_e,
    const float* __restrict__ el, const float* __restrict__ er,
    float* __restrict__ ee, float* __restrict__ eo)
{
  __shared__ __align__(16) short X[64*40];
  __shared__ float fc[64];
  const int e0 = blockIdx.x * 64;
  const int tid = threadIdx.x;
  const int w = tid >> 6, l = tid & 63, l15 = l & 15, lq = l >> 4;

  if (tid < 64){
    const float r = rij[e0 + tid];
    fc[tid] = (r < 5.0f) ? 0.5f*(cosf(0.62831853071795864f*r) + 1.0f) : 0.0f;
  }

  f32x4 acc1[2];
  acc1[0] = (f32x4)0.0f; acc1[1] = (f32x4)0.0f;
#pragma unroll
  for (int ks=0; ks<4; ++ks){
    const int k0 = ks*32 + lq*8;
    const int row = e0 + w*16 + l15;
    const bf16x8 af = load_a_f32(efeat + row*KIN + k0);
#pragma unroll
    for (int tc=0;tc<2;++tc){
      const int c = tc*16 + l15;
      const bf16x8 bfrag = *reinterpret_cast<const bf16x8*>(we1b + c*KIN + k0);
      acc1[tc] = __builtin_amdgcn_mfma_f32_16x16x32_bf16(af, bfrag, acc1[tc], 0,0,0);
    }
  }
  // D1: row = w*16 + lq*4 + j, col = tc*16 + l15
#pragma unroll
  for (int tc=0;tc<2;++tc){
    const int c = tc*16 + l15;
    const float b1 = be1[c];
#pragma unroll
    for (int j=0;j<4;++j){
      const int row = w*16 + lq*4 + j;
      X[row*40 + c] = f2b(sspf(acc1[tc][j] + b1));
    }
  }
  __syncthreads();

  f32x4 acc2[4][4];
#pragma unroll
  for (int a=0;a<4;++a)
#pragma unroll
    for (int b=0;b<4;++b) acc2[a][b] = (f32x4)0.0f;

  bf16x8 bfr[4];
  float aer[4], b2r[4];
#pragma unroll
  for (int tc=0;tc<4;++tc){
    const int c = w*64 + tc*16 + l15;
    bfr[tc] = *reinterpret_cast<const bf16x8*>(we2b + c*32 + lq*8);
    aer[tc] = attn_e[c];
    b2r[tc] = be2[c];
  }
#pragma unroll
  for (int tr=0;tr<4;++tr){
    const bf16x8 af = *reinterpret_cast<const bf16x8*>(&X[(tr*16 + l15)*40 + lq*8]);
#pragma unroll
    for (int tc=0;tc<4;++tc)
      acc2[tr][tc] = __builtin_amdgcn_mfma_f32_16x16x32_bf16(af, bfr[tc], acc2[tr][tc], 0,0,0);
  }

  float pe[4][4][2];
#pragma unroll
  for (int tr=0;tr<4;++tr)
#pragma unroll
    for (int j=0;j<4;++j){ pe[tr][j][0]=0.f; pe[tr][j][1]=0.f; }

#pragma unroll
  for (int tr=0;tr<4;++tr){
#pragma unroll
    for (int tc=0;tc<4;++tc){
      const int h2 = tc>>1;
#pragma unroll
      for (int j=0;j<4;++j){
        const int row = tr*16 + lq*4 + j;
        const float v = sspf(acc2[tr][tc][j] + b2r[tc]) * fc[row];
        pe[tr][j][h2] += v * aer[tc];
      }
    }
  }
#pragma unroll
  for (int m=1;m<16;m<<=1){
#pragma unroll
    for (int tr=0;tr<4;++tr)
#pragma unroll
      for (int j=0;j<4;++j){
        pe[tr][j][0] += __shfl_xor(pe[tr][j][0], m, 64);
        pe[tr][j][1] += __shfl_xor(pe[tr][j][1], m, 64);
      }
  }
#pragma unroll
  for (int tr=0;tr<4;++tr)
#pragma unroll
    for (int j=0;j<4;++j)
      if (l15 == tr*4 + j){
        const int edge = e0 + tr*16 + lq*4 + j;
        const int s = src[edge], d = dst[edge];
#pragma unroll
        for (int h2=0;h2<2;++h2){
          const int h = 2*w + h2;
          const float v = pe[tr][j][h2];
          ee[edge*8 + h] = v;
          const float x = el[s*8+h] + er[d*8+h] + v;
          eo[edge*8 + h] = (x > 0.f) ? x : 0.2f*x;
        }
      }
}

// ---------- CSR build ----------
__global__ void k_hist(const int* __restrict__ dst, int* __restrict__ deg){
  for (int i = blockIdx.x*blockDim.x + threadIdx.x; i < NE; i += gridDim.x*blockDim.x)
    atomicAdd(&deg[dst[i]], 1);
}
__global__ void k_scan(const int* __restrict__ deg, int* __restrict__ rowptr,
                       int* __restrict__ fillptr){
  __shared__ int buf[1024];
  __shared__ int carry;
  const int t = threadIdx.x;
  if (t == 0) carry = 0;
  __syncthreads();
  for (int base = 0; base < NN; base += 1024){
    const int i = base + t;
    const int v = (i < NN) ? deg[i] : 0;
    buf[t] = v;
    __syncthreads();
    for (int off=1; off<1024; off<<=1){
      const int add = (t >= off) ? buf[t-off] : 0;
      __syncthreads();
      buf[t] += add;
      __syncthreads();
    }
    const int excl = carry + buf[t] - v;
    if (i < NN){ rowptr[i] = excl; fillptr[i] = excl; }
    __syncthreads();
    if (t == 1023) carry += buf[1023];
    __syncthreads();
  }
  if (t == 0) rowptr[NN] = carry;
}
__global__ void k_fill(const int* __restrict__ dst, int* __restrict__ fillptr,
                       int* __restrict__ eid){
  for (int i = blockIdx.x*blockDim.x + threadIdx.x; i < NE; i += gridDim.x*blockDim.x){
    const int p = atomicAdd(&fillptr[dst[i]], 1);
    eid[p] = i;
  }
}

// ---------- edge softmax (per dst node, 1 wave/node) -> coef = softmax(e)*ee ----------
__global__ __launch_bounds__(256) void k_softmax(
    const int* __restrict__ rowptr, const int* __restrict__ eid,
    const float* __restrict__ eo, const float* __restrict__ ee,
    float* __restrict__ coef)
{
  const int node = blockIdx.x*4 + (threadIdx.x >> 6);
  const int l = threadIdx.x & 63;
  if (node >= NN) return;
  const int beg = rowptr[node], end = rowptr[node+1];

  float4 m0 = make_float4(-3e38f,-3e38f,-3e38f,-3e38f), m1 = m0;
  for (int p = beg + l; p < end; p += 64){
    const int id = eid[p];
    const float4* q = reinterpret_cast<const float4*>(eo + id*8);
    const float4 a = q[0], b = q[1];
    m0.x=fmaxf(m0.x,a.x); m0.y=fmaxf(m0.y,a.y); m0.z=fmaxf(m0.z,a.z); m0.w=fmaxf(m0.w,a.w);
    m1.x=fmaxf(m1.x,b.x); m1.y=fmaxf(m1.y,b.y); m1.z=fmaxf(m1.z,b.z); m1.w=fmaxf(m1.w,b.w);
  }
#pragma unroll
  for (int m=1;m<64;m<<=1){
    m0.x=fmaxf(m0.x,__shfl_xor(m0.x,m,64)); m0.y=fmaxf(m0.y,__shfl_xor(m0.y,m,64));
    m0.z=fmaxf(m0.z,__shfl_xor(m0.z,m,64)); m0.w=fmaxf(m0.w,__shfl_xor(m0.w,m,64));
    m1.x=fmaxf(m1.x,__shfl_xor(m1.x,m,64)); m1.y=fmaxf(m1.y,__shfl_xor(m1.y,m,64));
    m1.z=fmaxf(m1.z,__shfl_xor(m1.z,m,64)); m1.w=fmaxf(m1.w,__shfl_xor(m1.w,m,64));
  }
  float4 s0 = make_float4(0,0,0,0), s1 = s0;
  for (int p = beg + l; p < end; p += 64){
    const int id = eid[p];
    const float4* q = reinterpret_cast<const float4*>(eo + id*8);
    const float4 a = q[0], b = q[1];
    s0.x += expf(a.x-m0.x); s0.y += expf(a.y-m0.y); s0.z += expf(a.z-m0.z); s0.w += expf(a.w-m0.w);
    s1.x += expf(b.x-m1.x); s1.y += expf(b.y-m1.y); s1.z += expf(b.z-m1.z); s1.w += expf(b.w-m1.w);
  }
#pragma unroll
  for (int m=1;m<64;m<<=1){
    s0.x+=__shfl_xor(s0.x,m,64); s0.y+=__shfl_xor(s0.y,m,64);
    s0.z+=__shfl_xor(s0.z,m,64); s0.w+=__shfl_xor(s0.w,m,64);
    s1.x+=__shfl_xor(s1.x,m,64); s1.y+=__shfl_xor(s1.y,m,64);
    s1.z+=__shfl_xor(s1.z,m,64); s1.w+=__shfl_xor(s1.w,m,64);
  }
  const float4 i0 = make_float4(1.f/s0.x, 1.f/s0.y, 1.f/s0.z, 1.f/s0.w);
  const float4 i1 = make_float4(1.f/s1.x, 1.f/s1.y, 1.f/s1.z, 1.f/s1.w);
  for (int p = beg + l; p < end; p += 64){
    const int id = eid[p];
    const float4* q = reinterpret_cast<const float4*>(eo + id*8);
    const float4 a = q[0], b = q[1];
    const float4* qe = reinterpret_cast<const float4*>(ee + id*8);
    const float4 c0 = qe[0], c1 = qe[1];
    float4 o0, o1;
    o0.x = expf(a.x-m0.x)*i0.x*c0.x; o0.y = expf(a.y-m0.y)*i0.y*c0.y;
    o0.z = expf(a.z-m0.z)*i0.z*c0.z; o0.w = expf(a.w-m0.w)*i0.w*c0.w;
    o1.x = expf(b.x-m1.x)*i1.x*c1.x; o1.y = expf(b.y-m1.y)*i1.y*c1.y;
    o1.z = expf(b.z-m1.z)*i1.z*c1.z; o1.w = expf(b.w-m1.w)*i1.w*c1.w;
    float4* qo = reinterpret_cast<float4*>(coef + id*8);
    qo[0] = o0; qo[1] = o1;
  }
}

// ---------- aggregation: rst[n] = sum_e coef[e,h]*feat[src[e],h,d] + bias ----------
__global__ __launch_bounds__(256) void k_agg(
    const int* __restrict__ rowptr, const int* __restrict__ eid, const int* __restrict__ src,
    const float* __restrict__ coef, const short* __restrict__ featb,
    const float* __restrict__ bias, float* __restrict__ out)
{
  const int n = blockIdx.x;
  const int t = threadIdx.x;
  const int h = t >> 5;
  const int beg = rowptr[n], end = rowptr[n+1];
  float acc = 0.f;
  for (int p = beg; p < end; ++p){
    const int id = eid[p];
    const int s = src[id];
    const float c = coef[id*8 + h];
    acc += c * b2f(featb[s*HD + t]);
  }
  out[n*HD + t] = acc + bias[t];
}

extern "C" void kernel_launch(void* const* d_in, const int* in_sizes, int n_in,
                              void* d_out, int out_size, void* d_ws, size_t ws_size,
                              hipStream_t stream) {
  const float* nfeat  = (const float*)d_in[0];
  const float* efeat  = (const float*)d_in[1];
  const float* rij    = (const float*)d_in[2];
  const int*   src    = (const int*)d_in[3];
  const int*   dst    = (const int*)d_in[4];
  const float* W_fc   = (const float*)d_in[5];
  const float* W_e1   = (const float*)d_in[6];
  const float* b_e1   = (const float*)d_in[7];
  const float* W_e2   = (const float*)d_in[8];
  const float* b_e2   = (const float*)d_in[9];
  const float* attn_l = (const float*)d_in[10];
  const float* attn_r = (const float*)d_in[11];
  const float* attn_e = (const float*)d_in[12];
  const float* bias   = (const float*)d_in[13];
  float* out = (float*)d_out;

  size_t off = 0;
  auto carve = [&](size_t nbytes) -> void* {
    void* p = (char*)d_ws + off;
    off += (nbytes + 255) & ~(size_t)255;
    return p;
  };
  short* featb = (short*)carve((size_t)NN*HD*2);
  float* el    = (float*)carve((size_t)NN*8*4);
  float* er    = (float*)carve((size_t)NN*8*4);
  float* ee    = (float*)carve((size_t)NE*8*4);
  float* eo    = (float*)carve((size_t)NE*8*4);
  float* coef  = (float*)carve((size_t)NE*8*4);
  int* deg     = (int*)carve((size_t)NN*4);
  int* rowptr  = (int*)carve((size_t)(NN+1)*4);
  int* fillptr = (int*)carve((size_t)(NN+1)*4);
  int* eidb    = (int*)carve((size_t)NE*4);
  short* wfcb  = (short*)carve((size_t)HD*KIN*2);
  short* we1b  = (short*)carve((size_t)32*KIN*2);
  short* we2b  = (short*)carve((size_t)HD*32*2);

  hipMemsetAsync(deg, 0, (size_t)NN*4, stream);
  k_convert<<<128, 256, 0, stream>>>(W_fc, W_e1, W_e2, wfcb, we1b, we2b);
  k_feat<<<(NN+63)/64, 256, 0, stream>>>(nfeat, wfcb, attn_l, attn_r, featb, el, er);
  k_hist<<<1024, 256, 0, stream>>>(dst, deg);
  k_scan<<<1, 1024, 0, stream>>>(deg, rowptr, fillptr);
  k_fill<<<1024, 256, 0, stream>>>(dst, fillptr, eidb);
  k_edge<<<NE/64, 256, 0, stream>>>(efeat, rij, src, dst, we1b, b_e1, we2b, b_e2,
                                    attn_e, el, er, ee, eo);
  k_softmax<<<(NN+3)/4, 256, 0, stream>>>(rowptr, eidb, eo, ee, coef);
  k_agg<<<NN, 256, 0, stream>>>(rowptr, eidb, src, coef, featb, bias, out);
}

// Round 2
// 683.398 us; speedup vs baseline: 2.9197x; 2.9197x over previous
//
#include <hip/hip_runtime.h>
#include <hip/hip_bf16.h>

#define NN 50000
#define NE 800000
#define HD 256
#define KIN 128

typedef __attribute__((ext_vector_type(8))) short bf16x8;
typedef __attribute__((ext_vector_type(4))) float f32x4;

static __device__ __forceinline__ short f2b(float f){
  union { __hip_bfloat16 h; short s; } u;
  u.h = __float2bfloat16(f);
  return u.s;
}
static __device__ __forceinline__ float b2f(short s){
  union { __hip_bfloat16 h; short s; } u;
  u.s = s;
  return __bfloat162float(u.h);
}
// softplus(x) - log(2), fast: hw v_exp_f32 / v_log_f32 via __expf/__logf
static __device__ __forceinline__ float sspf(float x){
  const float t = __expf(-fabsf(x));
  return fmaxf(x, 0.0f) + __logf(1.0f + t) - 0.69314718055994531f;
}
static __device__ __forceinline__ bf16x8 load_a_f32(const float* __restrict__ p){
  const float4 x0 = *reinterpret_cast<const float4*>(p);
  const float4 x1 = *reinterpret_cast<const float4*>(p + 4);
  bf16x8 t;
  t[0]=f2b(x0.x); t[1]=f2b(x0.y); t[2]=f2b(x0.z); t[3]=f2b(x0.w);
  t[4]=f2b(x1.x); t[5]=f2b(x1.y); t[6]=f2b(x1.z); t[7]=f2b(x1.w);
  return t;
}

// ---------- weight fp32 -> bf16 ----------
__global__ void k_convert(const float* __restrict__ wfc, const float* __restrict__ we1,
                          const float* __restrict__ we2,
                          short* __restrict__ wfcb, short* __restrict__ we1b,
                          short* __restrict__ we2b){
  const int i = blockIdx.x*256 + threadIdx.x;
  if (i < HD*KIN) wfcb[i] = f2b(wfc[i]);
  if (i < 32*KIN) we1b[i] = f2b(we1[i]);
  if (i < HD*32)  we2b[i] = f2b(we2[i]);
}

// ---------- feat = nfeat @ W_fc^T  (+ el, er) ----------
__global__ __launch_bounds__(256) void k_feat(
    const float* __restrict__ nfeat, const short* __restrict__ wfcb,
    const float* __restrict__ attn_l, const float* __restrict__ attn_r,
    short* __restrict__ featb, float* __restrict__ el, float* __restrict__ er)
{
  const int n0 = blockIdx.x * 64;
  const int tid = threadIdx.x;
  const int w = tid >> 6, l = tid & 63, l15 = l & 15, lq = l >> 4;

  f32x4 acc[4][4];
#pragma unroll
  for (int a=0;a<4;++a)
#pragma unroll
    for (int b=0;b<4;++b) acc[a][b] = (f32x4)0.0f;

#pragma unroll
  for (int ks=0; ks<4; ++ks){
    const int k0 = ks*32 + lq*8;
    bf16x8 af[4];
#pragma unroll
    for (int tr=0; tr<4; ++tr){
      int row = n0 + tr*16 + l15;
      if (row >= NN) row = NN-1;
      af[tr] = load_a_f32(nfeat + row*KIN + k0);
    }
#pragma unroll
    for (int tc=0; tc<4; ++tc){
      const int c = w*64 + tc*16 + l15;
      const bf16x8 bfrag = *reinterpret_cast<const bf16x8*>(wfcb + c*KIN + k0);
#pragma unroll
      for (int tr=0; tr<4; ++tr)
        acc[tr][tc] = __builtin_amdgcn_mfma_f32_16x16x32_bf16(af[tr], bfrag, acc[tr][tc], 0,0,0);
    }
  }

  float alr[4], arr_[4];
#pragma unroll
  for (int tc=0;tc<4;++tc){
    const int c = w*64 + tc*16 + l15;
    alr[tc] = attn_l[c]; arr_[tc] = attn_r[c];
  }
  float pl[4][4][2], pr[4][4][2];
#pragma unroll
  for (int tr=0;tr<4;++tr)
#pragma unroll
    for (int j=0;j<4;++j){ pl[tr][j][0]=pl[tr][j][1]=0.f; pr[tr][j][0]=pr[tr][j][1]=0.f; }

  // D layout: row = tr*16 + lq*4 + j (node), col = w*64 + tc*16 + l15
#pragma unroll
  for (int tr=0;tr<4;++tr){
    const int rowb = tr*16 + lq*4;
#pragma unroll
    for (int tc=0;tc<4;++tc){
      const int c = w*64 + tc*16 + l15;
      const int h2 = tc>>1;
#pragma unroll
      for (int j=0;j<4;++j){
        const float v = acc[tr][tc][j];
        const int node = n0 + rowb + j;
        if (node < NN) featb[node*HD + c] = f2b(v);
        pl[tr][j][h2] += v*alr[tc];
        pr[tr][j][h2] += v*arr_[tc];
      }
    }
  }
#pragma unroll
  for (int m=1;m<16;m<<=1){
#pragma unroll
    for (int tr=0;tr<4;++tr)
#pragma unroll
      for (int j=0;j<4;++j){
        pl[tr][j][0] += __shfl_xor(pl[tr][j][0], m, 64);
        pl[tr][j][1] += __shfl_xor(pl[tr][j][1], m, 64);
        pr[tr][j][0] += __shfl_xor(pr[tr][j][0], m, 64);
        pr[tr][j][1] += __shfl_xor(pr[tr][j][1], m, 64);
      }
  }
#pragma unroll
  for (int tr=0;tr<4;++tr)
#pragma unroll
    for (int j=0;j<4;++j)
      if (l15 == tr*4+j){
        const int node = n0 + tr*16 + lq*4 + j;
        if (node < NN){
          el[node*8 + 2*w + 0] = pl[tr][j][0];
          el[node*8 + 2*w + 1] = pl[tr][j][1];
          er[node*8 + 2*w + 0] = pr[tr][j][0];
          er[node*8 + 2*w + 1] = pr[tr][j][1];
        }
      }
}

// ---------- CSR build ----------
__global__ void k_hist(const int* __restrict__ dst, int* __restrict__ deg){
  for (int i = blockIdx.x*blockDim.x + threadIdx.x; i < NE; i += gridDim.x*blockDim.x)
    atomicAdd(&deg[dst[i]], 1);
}

// 1024-thread single-block scan; wave shfl scan + thread-0 serial over 16 wave sums
__global__ __launch_bounds__(1024) void k_scan(const int* __restrict__ deg,
                                               int* __restrict__ rowptr,
                                               int* __restrict__ fillptr){
  __shared__ int wsum[16];
  __shared__ int carry_s;
  const int t = threadIdx.x;
  const int l = t & 63, wid = t >> 6;
  if (t == 0) carry_s = 0;
  __syncthreads();
  for (int base = 0; base < NN; base += 1024){
    const int i = base + t;
    const int v = (i < NN) ? deg[i] : 0;
    int x = v;
#pragma unroll
    for (int off=1; off<64; off<<=1){
      const int y = __shfl_up(x, off, 64);
      if (l >= off) x += y;
    }
    if (l == 63) wsum[wid] = x;
    __syncthreads();
    if (t == 0){
      int run = carry_s;
#pragma unroll
      for (int k=0;k<16;++k){ const int tmp = wsum[k]; wsum[k] = run; run += tmp; }
      carry_s = run;
    }
    __syncthreads();
    if (i < NN){
      const int excl = wsum[wid] + (x - v);
      rowptr[i] = excl; fillptr[i] = excl;
    }
    __syncthreads();
  }
  if (t == 0) rowptr[NN] = carry_s;
}

// fill: record CSR position per edge + src gathered into CSR order
__global__ void k_fill(const int* __restrict__ dst, const int* __restrict__ src,
                       int* __restrict__ fillptr,
                       int* __restrict__ epos, int* __restrict__ srcc){
  for (int i = blockIdx.x*blockDim.x + threadIdx.x; i < NE; i += gridDim.x*blockDim.x){
    const int p = atomicAdd(&fillptr[dst[i]], 1);
    epos[i] = p;
    srcc[p] = src[i];
  }
}

// ---------- fused edge MLP -> ee, e (written in CSR order via epos) ----------
__global__ __launch_bounds__(256) void k_edge(
    const float* __restrict__ efeat, const float* __restrict__ rij,
    const int* __restrict__ src, const int* __restrict__ dst,
    const int* __restrict__ epos,
    const short* __restrict__ we1b, const float* __restrict__ be1,
    const short* __restrict__ we2b, const float* __restrict__ be2,
    const float* __restrict__ attn_e,
    const float* __restrict__ el, const float* __restrict__ er,
    float* __restrict__ ee, float* __restrict__ eo)
{
  __shared__ __align__(16) short X[64*40];
  __shared__ float fc[64];
  const int e0 = blockIdx.x * 64;
  const int tid = threadIdx.x;
  const int w = tid >> 6, l = tid & 63, l15 = l & 15, lq = l >> 4;

  if (tid < 64){
    const float r = rij[e0 + tid];
    fc[tid] = (r < 5.0f) ? 0.5f*(__cosf(0.62831853071795864f*r) + 1.0f) : 0.0f;
  }

  f32x4 acc1[2];
  acc1[0] = (f32x4)0.0f; acc1[1] = (f32x4)0.0f;
#pragma unroll
  for (int ks=0; ks<4; ++ks){
    const int k0 = ks*32 + lq*8;
    const int row = e0 + w*16 + l15;
    const bf16x8 af = load_a_f32(efeat + row*KIN + k0);
#pragma unroll
    for (int tc=0;tc<2;++tc){
      const int c = tc*16 + l15;
      const bf16x8 bfrag = *reinterpret_cast<const bf16x8*>(we1b + c*KIN + k0);
      acc1[tc] = __builtin_amdgcn_mfma_f32_16x16x32_bf16(af, bfrag, acc1[tc], 0,0,0);
    }
  }
#pragma unroll
  for (int tc=0;tc<2;++tc){
    const int c = tc*16 + l15;
    const float b1 = be1[c];
#pragma unroll
    for (int j=0;j<4;++j){
      const int row = w*16 + lq*4 + j;
      X[row*40 + c] = f2b(sspf(acc1[tc][j] + b1));
    }
  }
  __syncthreads();

  f32x4 acc2[4][4];
#pragma unroll
  for (int a=0;a<4;++a)
#pragma unroll
    for (int b=0;b<4;++b) acc2[a][b] = (f32x4)0.0f;

  bf16x8 bfr[4];
  float aer[4], b2r[4];
#pragma unroll
  for (int tc=0;tc<4;++tc){
    const int c = w*64 + tc*16 + l15;
    bfr[tc] = *reinterpret_cast<const bf16x8*>(we2b + c*32 + lq*8);
    aer[tc] = attn_e[c];
    b2r[tc] = be2[c];
  }
#pragma unroll
  for (int tr=0;tr<4;++tr){
    const bf16x8 af = *reinterpret_cast<const bf16x8*>(&X[(tr*16 + l15)*40 + lq*8]);
#pragma unroll
    for (int tc=0;tc<4;++tc)
      acc2[tr][tc] = __builtin_amdgcn_mfma_f32_16x16x32_bf16(af, bfr[tc], acc2[tr][tc], 0,0,0);
  }

  float pe[4][4][2];
#pragma unroll
  for (int tr=0;tr<4;++tr)
#pragma unroll
    for (int j=0;j<4;++j){ pe[tr][j][0]=0.f; pe[tr][j][1]=0.f; }

#pragma unroll
  for (int tr=0;tr<4;++tr){
#pragma unroll
    for (int tc=0;tc<4;++tc){
      const int h2 = tc>>1;
#pragma unroll
      for (int j=0;j<4;++j){
        const int row = tr*16 + lq*4 + j;
        const float v = sspf(acc2[tr][tc][j] + b2r[tc]) * fc[row];
        pe[tr][j][h2] += v * aer[tc];
      }
    }
  }
#pragma unroll
  for (int m=1;m<16;m<<=1){
#pragma unroll
    for (int tr=0;tr<4;++tr)
#pragma unroll
      for (int j=0;j<4;++j){
        pe[tr][j][0] += __shfl_xor(pe[tr][j][0], m, 64);
        pe[tr][j][1] += __shfl_xor(pe[tr][j][1], m, 64);
      }
  }
#pragma unroll
  for (int tr=0;tr<4;++tr)
#pragma unroll
    for (int j=0;j<4;++j)
      if (l15 == tr*4 + j){
        const int edge = e0 + tr*16 + lq*4 + j;
        const int s = src[edge], d = dst[edge];
        const int p = epos[edge];
#pragma unroll
        for (int h2=0;h2<2;++h2){
          const int h = 2*w + h2;
          const float v = pe[tr][j][h2];
          ee[p*8 + h] = v;
          const float x = el[s*8+h] + er[d*8+h] + v;
          eo[p*8 + h] = (x > 0.f) ? x : 0.2f*x;
        }
      }
}

// ---------- edge softmax (CSR-contiguous) -> coef = softmax(e)*ee ----------
__global__ __launch_bounds__(256) void k_softmax(
    const int* __restrict__ rowptr,
    const float* __restrict__ eo, const float* __restrict__ ee,
    float* __restrict__ coef)
{
  const int node = blockIdx.x*4 + (threadIdx.x >> 6);
  const int l = threadIdx.x & 63;
  if (node >= NN) return;
  const int beg = rowptr[node], end = rowptr[node+1];

  float4 m0 = make_float4(-3e38f,-3e38f,-3e38f,-3e38f), m1 = m0;
  for (int p = beg + l; p < end; p += 64){
    const float4* q = reinterpret_cast<const float4*>(eo + (size_t)p*8);
    const float4 a = q[0], b = q[1];
    m0.x=fmaxf(m0.x,a.x); m0.y=fmaxf(m0.y,a.y); m0.z=fmaxf(m0.z,a.z); m0.w=fmaxf(m0.w,a.w);
    m1.x=fmaxf(m1.x,b.x); m1.y=fmaxf(m1.y,b.y); m1.z=fmaxf(m1.z,b.z); m1.w=fmaxf(m1.w,b.w);
  }
#pragma unroll
  for (int m=1;m<64;m<<=1){
    m0.x=fmaxf(m0.x,__shfl_xor(m0.x,m,64)); m0.y=fmaxf(m0.y,__shfl_xor(m0.y,m,64));
    m0.z=fmaxf(m0.z,__shfl_xor(m0.z,m,64)); m0.w=fmaxf(m0.w,__shfl_xor(m0.w,m,64));
    m1.x=fmaxf(m1.x,__shfl_xor(m1.x,m,64)); m1.y=fmaxf(m1.y,__shfl_xor(m1.y,m,64));
    m1.z=fmaxf(m1.z,__shfl_xor(m1.z,m,64)); m1.w=fmaxf(m1.w,__shfl_xor(m1.w,m,64));
  }
  float4 s0 = make_float4(0,0,0,0), s1 = s0;
  for (int p = beg + l; p < end; p += 64){
    const float4* q = reinterpret_cast<const float4*>(eo + (size_t)p*8);
    const float4 a = q[0], b = q[1];
    s0.x += __expf(a.x-m0.x); s0.y += __expf(a.y-m0.y); s0.z += __expf(a.z-m0.z); s0.w += __expf(a.w-m0.w);
    s1.x += __expf(b.x-m1.x); s1.y += __expf(b.y-m1.y); s1.z += __expf(b.z-m1.z); s1.w += __expf(b.w-m1.w);
  }
#pragma unroll
  for (int m=1;m<64;m<<=1){
    s0.x+=__shfl_xor(s0.x,m,64); s0.y+=__shfl_xor(s0.y,m,64);
    s0.z+=__shfl_xor(s0.z,m,64); s0.w+=__shfl_xor(s0.w,m,64);
    s1.x+=__shfl_xor(s1.x,m,64); s1.y+=__shfl_xor(s1.y,m,64);
    s1.z+=__shfl_xor(s1.z,m,64); s1.w+=__shfl_xor(s1.w,m,64);
  }
  const float4 i0 = make_float4(1.f/s0.x, 1.f/s0.y, 1.f/s0.z, 1.f/s0.w);
  const float4 i1 = make_float4(1.f/s1.x, 1.f/s1.y, 1.f/s1.z, 1.f/s1.w);
  for (int p = beg + l; p < end; p += 64){
    const float4* q = reinterpret_cast<const float4*>(eo + (size_t)p*8);
    const float4 a = q[0], b = q[1];
    const float4* qe = reinterpret_cast<const float4*>(ee + (size_t)p*8);
    const float4 c0 = qe[0], c1 = qe[1];
    float4 o0, o1;
    o0.x = __expf(a.x-m0.x)*i0.x*c0.x; o0.y = __expf(a.y-m0.y)*i0.y*c0.y;
    o0.z = __expf(a.z-m0.z)*i0.z*c0.z; o0.w = __expf(a.w-m0.w)*i0.w*c0.w;
    o1.x = __expf(b.x-m1.x)*i1.x*c1.x; o1.y = __expf(b.y-m1.y)*i1.y*c1.y;
    o1.z = __expf(b.z-m1.z)*i1.z*c1.z; o1.w = __expf(b.w-m1.w)*i1.w*c1.w;
    float4* qo = reinterpret_cast<float4*>(coef + (size_t)p*8);
    qo[0] = o0; qo[1] = o1;
  }
}

// ---------- aggregation ----------
__global__ __launch_bounds__(256) void k_agg(
    const int* __restrict__ rowptr, const int* __restrict__ srcc,
    const float* __restrict__ coef, const short* __restrict__ featb,
    const float* __restrict__ bias, float* __restrict__ out)
{
  const int n = blockIdx.x;
  const int t = threadIdx.x;
  const int h = t >> 5;
  const int beg = rowptr[n], end = rowptr[n+1];
  float acc = 0.f;
  for (int p = beg; p < end; ++p){
    const int s = srcc[p];
    const float c = coef[(size_t)p*8 + h];
    acc += c * b2f(featb[s*HD + t]);
  }
  out[n*HD + t] = acc + bias[t];
}

extern "C" void kernel_launch(void* const* d_in, const int* in_sizes, int n_in,
                              void* d_out, int out_size, void* d_ws, size_t ws_size,
                              hipStream_t stream) {
  const float* nfeat  = (const float*)d_in[0];
  const float* efeat  = (const float*)d_in[1];
  const float* rij    = (const float*)d_in[2];
  const int*   src    = (const int*)d_in[3];
  const int*   dst    = (const int*)d_in[4];
  const float* W_fc   = (const float*)d_in[5];
  const float* W_e1   = (const float*)d_in[6];
  const float* b_e1   = (const float*)d_in[7];
  const float* W_e2   = (const float*)d_in[8];
  const float* b_e2   = (const float*)d_in[9];
  const float* attn_l = (const float*)d_in[10];
  const float* attn_r = (const float*)d_in[11];
  const float* attn_e = (const float*)d_in[12];
  const float* bias   = (const float*)d_in[13];
  float* out = (float*)d_out;

  size_t off = 0;
  auto carve = [&](size_t nbytes) -> void* {
    void* p = (char*)d_ws + off;
    off += (nbytes + 255) & ~(size_t)255;
    return p;
  };
  short* featb = (short*)carve((size_t)NN*HD*2);
  float* el    = (float*)carve((size_t)NN*8*4);
  float* er    = (float*)carve((size_t)NN*8*4);
  float* ee    = (float*)carve((size_t)NE*8*4);
  float* eo    = (float*)carve((size_t)NE*8*4);
  float* coef  = (float*)carve((size_t)NE*8*4);
  int* deg     = (int*)carve((size_t)NN*4);
  int* rowptr  = (int*)carve((size_t)(NN+1)*4);
  int* fillptr = (int*)carve((size_t)(NN+1)*4);
  int* epos    = (int*)carve((size_t)NE*4);
  int* srcc    = (int*)carve((size_t)NE*4);
  short* wfcb  = (short*)carve((size_t)HD*KIN*2);
  short* we1b  = (short*)carve((size_t)32*KIN*2);
  short* we2b  = (short*)carve((size_t)HD*32*2);

  hipMemsetAsync(deg, 0, (size_t)NN*4, stream);
  k_convert<<<128, 256, 0, stream>>>(W_fc, W_e1, W_e2, wfcb, we1b, we2b);
  k_feat<<<(NN+63)/64, 256, 0, stream>>>(nfeat, wfcb, attn_l, attn_r, featb, el, er);
  k_hist<<<1024, 256, 0, stream>>>(dst, deg);
  k_scan<<<1, 1024, 0, stream>>>(deg, rowptr, fillptr);
  k_fill<<<1024, 256, 0, stream>>>(dst, src, fillptr, epos, srcc);
  k_edge<<<NE/64, 256, 0, stream>>>(efeat, rij, src, dst, epos, we1b, b_e1, we2b, b_e2,
                                    attn_e, el, er, ee, eo);
  k_softmax<<<(NN+3)/4, 256, 0, stream>>>(rowptr, eo, ee, coef);
  k_agg<<<NN, 256, 0, stream>>>(rowptr, srcc, coef, featb, bias, out);
}

// Round 3
// 573.773 us; speedup vs baseline: 3.4775x; 1.1911x over previous
//
#include <hip/hip_runtime.h>
#include <hip/hip_bf16.h>

#define NN 50000
#define NE 800000
#define HD 256
#define KIN 128
#define SCAN_B 49

typedef __attribute__((ext_vector_type(8))) short bf16x8;
typedef __attribute__((ext_vector_type(4))) float f32x4;

static __device__ __forceinline__ short f2b(float f){
  union { __hip_bfloat16 h; short s; } u;
  u.h = __float2bfloat16(f);
  return u.s;
}
static __device__ __forceinline__ float b2f(short s){
  union { __hip_bfloat16 h; short s; } u;
  u.s = s;
  return __bfloat162float(u.h);
}
// softplus(x) - log(2), hw transcendentals
static __device__ __forceinline__ float sspf(float x){
  const float t = __expf(-fabsf(x));
  return fmaxf(x, 0.0f) + __logf(1.0f + t) - 0.69314718055994531f;
}
static __device__ __forceinline__ bf16x8 load_a_f32(const float* __restrict__ p){
  const float4 x0 = *reinterpret_cast<const float4*>(p);
  const float4 x1 = *reinterpret_cast<const float4*>(p + 4);
  bf16x8 t;
  t[0]=f2b(x0.x); t[1]=f2b(x0.y); t[2]=f2b(x0.z); t[3]=f2b(x0.w);
  t[4]=f2b(x1.x); t[5]=f2b(x1.y); t[6]=f2b(x1.z); t[7]=f2b(x1.w);
  return t;
}
static __device__ __forceinline__ f32x4 leaky4(f32x4 x){
  f32x4 r;
#pragma unroll
  for (int k=0;k<4;++k) r[k] = x[k] > 0.f ? x[k] : 0.2f*x[k];
  return r;
}
static __device__ __forceinline__ f32x4 max4(f32x4 a, f32x4 b){
  f32x4 r;
#pragma unroll
  for (int k=0;k<4;++k) r[k] = fmaxf(a[k], b[k]);
  return r;
}
static __device__ __forceinline__ f32x4 exp4(f32x4 x){
  f32x4 r;
#pragma unroll
  for (int k=0;k<4;++k) r[k] = __expf(x[k]);
  return r;
}

// ---------- weight fp32 -> bf16 ----------
__global__ void k_convert(const float* __restrict__ wfc, const float* __restrict__ we1,
                          const float* __restrict__ we2,
                          short* __restrict__ wfcb, short* __restrict__ we1b,
                          short* __restrict__ we2b){
  const int i = blockIdx.x*256 + threadIdx.x;
  if (i < HD*KIN) wfcb[i] = f2b(wfc[i]);
  if (i < 32*KIN) we1b[i] = f2b(we1[i]);
  if (i < HD*32)  we2b[i] = f2b(we2[i]);
}

// ---------- feat = nfeat @ W_fc^T  (+ el, er) ----------
__global__ __launch_bounds__(256) void k_feat(
    const float* __restrict__ nfeat, const short* __restrict__ wfcb,
    const float* __restrict__ attn_l, const float* __restrict__ attn_r,
    short* __restrict__ featb, float* __restrict__ el, float* __restrict__ er)
{
  const int n0 = blockIdx.x * 64;
  const int tid = threadIdx.x;
  const int w = tid >> 6, l = tid & 63, l15 = l & 15, lq = l >> 4;

  f32x4 acc[4][4];
#pragma unroll
  for (int a=0;a<4;++a)
#pragma unroll
    for (int b=0;b<4;++b) acc[a][b] = (f32x4)0.0f;

#pragma unroll
  for (int ks=0; ks<4; ++ks){
    const int k0 = ks*32 + lq*8;
    bf16x8 af[4];
#pragma unroll
    for (int tr=0; tr<4; ++tr){
      int row = n0 + tr*16 + l15;
      if (row >= NN) row = NN-1;
      af[tr] = load_a_f32(nfeat + row*KIN + k0);
    }
#pragma unroll
    for (int tc=0; tc<4; ++tc){
      const int c = w*64 + tc*16 + l15;
      const bf16x8 bfrag = *reinterpret_cast<const bf16x8*>(wfcb + c*KIN + k0);
#pragma unroll
      for (int tr=0; tr<4; ++tr)
        acc[tr][tc] = __builtin_amdgcn_mfma_f32_16x16x32_bf16(af[tr], bfrag, acc[tr][tc], 0,0,0);
    }
  }

  float alr[4], arr_[4];
#pragma unroll
  for (int tc=0;tc<4;++tc){
    const int c = w*64 + tc*16 + l15;
    alr[tc] = attn_l[c]; arr_[tc] = attn_r[c];
  }
  float pl[4][4][2], pr[4][4][2];
#pragma unroll
  for (int tr=0;tr<4;++tr)
#pragma unroll
    for (int j=0;j<4;++j){ pl[tr][j][0]=pl[tr][j][1]=0.f; pr[tr][j][0]=pr[tr][j][1]=0.f; }

  // D layout: row = tr*16 + lq*4 + j (node), col = w*64 + tc*16 + l15
#pragma unroll
  for (int tr=0;tr<4;++tr){
    const int rowb = tr*16 + lq*4;
#pragma unroll
    for (int tc=0;tc<4;++tc){
      const int c = w*64 + tc*16 + l15;
      const int h2 = tc>>1;
#pragma unroll
      for (int j=0;j<4;++j){
        const float v = acc[tr][tc][j];
        const int node = n0 + rowb + j;
        if (node < NN) featb[node*HD + c] = f2b(v);
        pl[tr][j][h2] += v*alr[tc];
        pr[tr][j][h2] += v*arr_[tc];
      }
    }
  }
#pragma unroll
  for (int m=1;m<16;m<<=1){
#pragma unroll
    for (int tr=0;tr<4;++tr)
#pragma unroll
      for (int j=0;j<4;++j){
        pl[tr][j][0] += __shfl_xor(pl[tr][j][0], m, 64);
        pl[tr][j][1] += __shfl_xor(pl[tr][j][1], m, 64);
        pr[tr][j][0] += __shfl_xor(pr[tr][j][0], m, 64);
        pr[tr][j][1] += __shfl_xor(pr[tr][j][1], m, 64);
      }
  }
#pragma unroll
  for (int tr=0;tr<4;++tr)
#pragma unroll
    for (int j=0;j<4;++j)
      if (l15 == tr*4+j){
        const int node = n0 + tr*16 + lq*4 + j;
        if (node < NN){
          el[node*8 + 2*w + 0] = pl[tr][j][0];
          el[node*8 + 2*w + 1] = pl[tr][j][1];
          er[node*8 + 2*w + 0] = pr[tr][j][0];
          er[node*8 + 2*w + 1] = pr[tr][j][1];
        }
      }
}

// ---------- CSR build ----------
__global__ void k_hist(const int* __restrict__ dst, int* __restrict__ deg){
  for (int i = blockIdx.x*blockDim.x + threadIdx.x; i < NE; i += gridDim.x*blockDim.x)
    atomicAdd(&deg[dst[i]], 1);
}

__global__ __launch_bounds__(1024) void k_scanA(const int* __restrict__ deg,
                                                int* __restrict__ bsum){
  __shared__ int ws[16];
  const int t = threadIdx.x;
  const int i = blockIdx.x*1024 + t;
  int v = (i < NN) ? deg[i] : 0;
#pragma unroll
  for (int m=1;m<64;m<<=1) v += __shfl_xor(v, m, 64);
  if ((t & 63) == 0) ws[t >> 6] = v;
  __syncthreads();
  if (t == 0){
    int s = 0;
#pragma unroll
    for (int k=0;k<16;++k) s += ws[k];
    bsum[blockIdx.x] = s;
  }
}
__global__ void k_scanB(const int* __restrict__ bsum, int* __restrict__ boff,
                        int* __restrict__ total){
  const int t = threadIdx.x;  // 64 threads
  const int v = (t < SCAN_B) ? bsum[t] : 0;
  int x = v;
#pragma unroll
  for (int off=1; off<64; off<<=1){
    const int y = __shfl_up(x, off, 64);
    if (t >= off) x += y;
  }
  if (t < SCAN_B) boff[t] = x - v;
  if (t == 63) *total = x;
}
__global__ __launch_bounds__(1024) void k_scanC(const int* __restrict__ deg,
                                                const int* __restrict__ boff,
                                                const int* __restrict__ total,
                                                int* __restrict__ rowptr,
                                                int* __restrict__ fillptr){
  __shared__ int ws[16];
  const int t = threadIdx.x, l = t & 63, wid = t >> 6;
  const int i = blockIdx.x*1024 + t;
  const int v = (i < NN) ? deg[i] : 0;
  int x = v;
#pragma unroll
  for (int off=1; off<64; off<<=1){
    const int y = __shfl_up(x, off, 64);
    if (l >= off) x += y;
  }
  if (l == 63) ws[wid] = x;
  __syncthreads();
  if (t == 0){
    int run = 0;
#pragma unroll
    for (int k=0;k<16;++k){ const int tmp = ws[k]; ws[k] = run; run += tmp; }
  }
  __syncthreads();
  if (i < NN){
    const int excl = boff[blockIdx.x] + ws[wid] + (x - v);
    rowptr[i] = excl; fillptr[i] = excl;
  }
  if (blockIdx.x == 0 && t == 0) rowptr[NN] = *total;
}

__global__ void k_fill(const int* __restrict__ dst, const int* __restrict__ src,
                       int* __restrict__ fillptr,
                       int* __restrict__ epos, int* __restrict__ srcc){
  for (int i = blockIdx.x*blockDim.x + threadIdx.x; i < NE; i += gridDim.x*blockDim.x){
    const int p = atomicAdd(&fillptr[dst[i]], 1);
    epos[i] = p;
    srcc[p] = src[i];
  }
}

// ---------- fused edge MLP -> ee (CSR order) ----------
// GEMM2 is operand-SWAPPED: D rows = channels (regs), cols = edges (lanes) so the
// attn_edge dot reduces in-register + 2 shfl steps over lq.
__global__ __launch_bounds__(256, 5) void k_edge(
    const float* __restrict__ efeat, const float* __restrict__ rij,
    const int* __restrict__ epos,
    const short* __restrict__ we1b, const float* __restrict__ be1,
    const short* __restrict__ we2b, const float* __restrict__ be2,
    const float* __restrict__ attn_e,
    float* __restrict__ ee)
{
  __shared__ __align__(16) short X[64*40];
  __shared__ float fc[64];
  const int e0 = blockIdx.x * 64;
  const int tid = threadIdx.x;
  const int w = tid >> 6, l = tid & 63, l15 = l & 15, lq = l >> 4;

  if (tid < 64){
    const float r = rij[e0 + tid];
    fc[tid] = (r < 5.0f) ? 0.5f*(__cosf(0.62831853071795864f*r) + 1.0f) : 0.0f;
  }

  // GEMM1: edges w*16..+15 x hidden 32
  f32x4 acc1[2];
  acc1[0] = (f32x4)0.0f; acc1[1] = (f32x4)0.0f;
#pragma unroll
  for (int ks=0; ks<4; ++ks){
    const int k0 = ks*32 + lq*8;
    const bf16x8 af = load_a_f32(efeat + (size_t)(e0 + w*16 + l15)*KIN + k0);
#pragma unroll
    for (int tc=0;tc<2;++tc){
      const bf16x8 bfrag = *reinterpret_cast<const bf16x8*>(we1b + (tc*16 + l15)*KIN + k0);
      acc1[tc] = __builtin_amdgcn_mfma_f32_16x16x32_bf16(af, bfrag, acc1[tc], 0,0,0);
    }
  }
#pragma unroll
  for (int tc=0;tc<2;++tc){
    const int c = tc*16 + l15;
    const float b1 = be1[c];
#pragma unroll
    for (int j=0;j<4;++j){
      const int row = w*16 + lq*4 + j;
      X[row*40 + c] = f2b(sspf(acc1[tc][j] + b1));
    }
  }
  __syncthreads();

  // GEMM2 swapped: wave w owns channels [w*64, w*64+64) = heads 2w, 2w+1
  bf16x8 xfrag[4];
  float fcr[4];
#pragma unroll
  for (int cb=0;cb<4;++cb){
    xfrag[cb] = *reinterpret_cast<const bf16x8*>(&X[(cb*16 + l15)*40 + lq*8]);
    fcr[cb] = fc[cb*16 + l15];
  }

  float pe[4][2];
#pragma unroll
  for (int cb=0;cb<4;++cb){ pe[cb][0]=0.f; pe[cb][1]=0.f; }

#pragma unroll
  for (int rah=0; rah<2; ++rah){   // channel half = head w*2+rah
    f32x4 acc2[2][4];
#pragma unroll
    for (int r2=0;r2<2;++r2)
#pragma unroll
      for (int cb=0;cb<4;++cb) acc2[r2][cb] = (f32x4)0.0f;
    bf16x8 wfr[2];
#pragma unroll
    for (int r2=0;r2<2;++r2){
      const int ch = w*64 + (rah*2 + r2)*16 + l15;
      wfr[r2] = *reinterpret_cast<const bf16x8*>(we2b + ch*32 + lq*8);
    }
#pragma unroll
    for (int r2=0;r2<2;++r2)
#pragma unroll
      for (int cb=0;cb<4;++cb)
        acc2[r2][cb] = __builtin_amdgcn_mfma_f32_16x16x32_bf16(wfr[r2], xfrag[cb], acc2[r2][cb], 0,0,0);

#pragma unroll
    for (int r2=0;r2<2;++r2){
      const int ra = rah*2 + r2;
      const int cbase = w*64 + ra*16 + lq*4;
      const f32x4 b2v = *reinterpret_cast<const f32x4*>(be2 + cbase);
      const f32x4 aev = *reinterpret_cast<const f32x4*>(attn_e + cbase);
#pragma unroll
      for (int cb=0;cb<4;++cb){
#pragma unroll
        for (int j=0;j<4;++j){
          const float v = sspf(acc2[r2][cb][j] + b2v[j]);
          pe[cb][rah] += v * aev[j];
        }
      }
    }
  }
  // reduce over lq (lane bits 4,5)
#pragma unroll
  for (int cb=0;cb<4;++cb){
    pe[cb][0] += __shfl_xor(pe[cb][0], 16, 64);
    pe[cb][1] += __shfl_xor(pe[cb][1], 16, 64);
    pe[cb][0] += __shfl_xor(pe[cb][0], 32, 64);
    pe[cb][1] += __shfl_xor(pe[cb][1], 32, 64);
  }
  if (lq == 0){
#pragma unroll
    for (int cb=0;cb<4;++cb){
      const int p = epos[e0 + cb*16 + l15];
      float2 val;
      val.x = pe[cb][0] * fcr[cb];
      val.y = pe[cb][1] * fcr[cb];
      *reinterpret_cast<float2*>(ee + (size_t)p*8 + w*2) = val;
    }
  }
}

// ---------- edge softmax (16-lane groups, leaky fused) -> coef ----------
__global__ __launch_bounds__(256) void k_softmax(
    const int* __restrict__ rowptr, const int* __restrict__ srcc,
    const float* __restrict__ el, const float* __restrict__ er,
    const float* __restrict__ ee, float* __restrict__ coef)
{
  const int node = blockIdx.x*16 + (threadIdx.x >> 4);
  const int l = threadIdx.x & 15;
  if (node >= NN) return;
  const int beg = rowptr[node], end = rowptr[node+1];
  const f32x4 er0 = *reinterpret_cast<const f32x4*>(er + (size_t)node*8);
  const f32x4 er1 = *reinterpret_cast<const f32x4*>(er + (size_t)node*8 + 4);

  f32x4 m0 = (f32x4)(-3e38f), m1 = (f32x4)(-3e38f);
  for (int p = beg + l; p < end; p += 16){
    const int s = srcc[p];
    const f32x4 e0v = *reinterpret_cast<const f32x4*>(ee + (size_t)p*8);
    const f32x4 e1v = *reinterpret_cast<const f32x4*>(ee + (size_t)p*8 + 4);
    const f32x4 l0 = *reinterpret_cast<const f32x4*>(el + (size_t)s*8);
    const f32x4 l1 = *reinterpret_cast<const f32x4*>(el + (size_t)s*8 + 4);
    m0 = max4(m0, leaky4(e0v + l0 + er0));
    m1 = max4(m1, leaky4(e1v + l1 + er1));
  }
#pragma unroll
  for (int m=1;m<16;m<<=1){
#pragma unroll
    for (int k=0;k<4;++k){
      m0[k] = fmaxf(m0[k], __shfl_xor(m0[k], m, 64));
      m1[k] = fmaxf(m1[k], __shfl_xor(m1[k], m, 64));
    }
  }
  f32x4 s0 = (f32x4)0.0f, s1 = (f32x4)0.0f;
  for (int p = beg + l; p < end; p += 16){
    const int s = srcc[p];
    const f32x4 e0v = *reinterpret_cast<const f32x4*>(ee + (size_t)p*8);
    const f32x4 e1v = *reinterpret_cast<const f32x4*>(ee + (size_t)p*8 + 4);
    const f32x4 l0 = *reinterpret_cast<const f32x4*>(el + (size_t)s*8);
    const f32x4 l1 = *reinterpret_cast<const f32x4*>(el + (size_t)s*8 + 4);
    s0 += exp4(leaky4(e0v + l0 + er0) - m0);
    s1 += exp4(leaky4(e1v + l1 + er1) - m1);
  }
#pragma unroll
  for (int m=1;m<16;m<<=1){
#pragma unroll
    for (int k=0;k<4;++k){
      s0[k] += __shfl_xor(s0[k], m, 64);
      s1[k] += __shfl_xor(s1[k], m, 64);
    }
  }
  f32x4 i0, i1;
#pragma unroll
  for (int k=0;k<4;++k){ i0[k] = 1.0f/s0[k]; i1[k] = 1.0f/s1[k]; }
  for (int p = beg + l; p < end; p += 16){
    const int s = srcc[p];
    const f32x4 e0v = *reinterpret_cast<const f32x4*>(ee + (size_t)p*8);
    const f32x4 e1v = *reinterpret_cast<const f32x4*>(ee + (size_t)p*8 + 4);
    const f32x4 l0 = *reinterpret_cast<const f32x4*>(el + (size_t)s*8);
    const f32x4 l1 = *reinterpret_cast<const f32x4*>(el + (size_t)s*8 + 4);
    const f32x4 o0 = exp4(leaky4(e0v + l0 + er0) - m0) * i0 * e0v;
    const f32x4 o1 = exp4(leaky4(e1v + l1 + er1) - m1) * i1 * e1v;
    *reinterpret_cast<f32x4*>(coef + (size_t)p*8) = o0;
    *reinterpret_cast<f32x4*>(coef + (size_t)p*8 + 4) = o1;
  }
}

// ---------- aggregation: 4 waves = 4 edges in flight ----------
__global__ __launch_bounds__(256) void k_agg(
    const int* __restrict__ rowptr, const int* __restrict__ srcc,
    const float* __restrict__ coef, const short* __restrict__ featb,
    const float* __restrict__ bias, float* __restrict__ out)
{
  __shared__ float red[4][64][4];
  const int n = blockIdx.x;
  const int t = threadIdx.x, l = t & 63, g = t >> 6;
  const int c0 = l*4, h = l >> 3;
  const int beg = rowptr[n], end = rowptr[n+1];
  float a0=0.f, a1=0.f, a2=0.f, a3=0.f;
  for (int p = beg + g; p < end; p += 4){
    const int s = srcc[p];
    const float cf = coef[(size_t)p*8 + h];
    const short4 fv = *reinterpret_cast<const short4*>(featb + (size_t)s*HD + c0);
    a0 += cf*b2f(fv.x); a1 += cf*b2f(fv.y); a2 += cf*b2f(fv.z); a3 += cf*b2f(fv.w);
  }
  red[g][l][0]=a0; red[g][l][1]=a1; red[g][l][2]=a2; red[g][l][3]=a3;
  __syncthreads();
  if (t < 64){
    const float4 b = *reinterpret_cast<const float4*>(bias + t*4);
    float4 o;
    o.x = red[0][t][0]+red[1][t][0]+red[2][t][0]+red[3][t][0] + b.x;
    o.y = red[0][t][1]+red[1][t][1]+red[2][t][1]+red[3][t][1] + b.y;
    o.z = red[0][t][2]+red[1][t][2]+red[2][t][2]+red[3][t][2] + b.z;
    o.w = red[0][t][3]+red[1][t][3]+red[2][t][3]+red[3][t][3] + b.w;
    *reinterpret_cast<float4*>(out + (size_t)n*HD + t*4) = o;
  }
}

extern "C" void kernel_launch(void* const* d_in, const int* in_sizes, int n_in,
                              void* d_out, int out_size, void* d_ws, size_t ws_size,
                              hipStream_t stream) {
  const float* nfeat  = (const float*)d_in[0];
  const float* efeat  = (const float*)d_in[1];
  const float* rij    = (const float*)d_in[2];
  const int*   src    = (const int*)d_in[3];
  const int*   dst    = (const int*)d_in[4];
  const float* W_fc   = (const float*)d_in[5];
  const float* W_e1   = (const float*)d_in[6];
  const float* b_e1   = (const float*)d_in[7];
  const float* W_e2   = (const float*)d_in[8];
  const float* b_e2   = (const float*)d_in[9];
  const float* attn_l = (const float*)d_in[10];
  const float* attn_r = (const float*)d_in[11];
  const float* attn_e = (const float*)d_in[12];
  const float* bias   = (const float*)d_in[13];
  float* out = (float*)d_out;

  size_t off = 0;
  auto carve = [&](size_t nbytes) -> void* {
    void* p = (char*)d_ws + off;
    off += (nbytes + 255) & ~(size_t)255;
    return p;
  };
  short* featb = (short*)carve((size_t)NN*HD*2);
  float* el    = (float*)carve((size_t)NN*8*4);
  float* er    = (float*)carve((size_t)NN*8*4);
  float* ee    = (float*)carve((size_t)NE*8*4);
  float* coef  = (float*)carve((size_t)NE*8*4);
  int* deg     = (int*)carve((size_t)NN*4);
  int* rowptr  = (int*)carve((size_t)(NN+1)*4);
  int* fillptr = (int*)carve((size_t)(NN+1)*4);
  int* epos    = (int*)carve((size_t)NE*4);
  int* srcc    = (int*)carve((size_t)NE*4);
  int* bsum    = (int*)carve((size_t)SCAN_B*4);
  int* boff    = (int*)carve((size_t)SCAN_B*4);
  int* total   = (int*)carve(4);
  short* wfcb  = (short*)carve((size_t)HD*KIN*2);
  short* we1b  = (short*)carve((size_t)32*KIN*2);
  short* we2b  = (short*)carve((size_t)HD*32*2);

  hipMemsetAsync(deg, 0, (size_t)NN*4, stream);
  k_convert<<<128, 256, 0, stream>>>(W_fc, W_e1, W_e2, wfcb, we1b, we2b);
  k_feat<<<(NN+63)/64, 256, 0, stream>>>(nfeat, wfcb, attn_l, attn_r, featb, el, er);
  k_hist<<<1024, 256, 0, stream>>>(dst, deg);
  k_scanA<<<SCAN_B, 1024, 0, stream>>>(deg, bsum);
  k_scanB<<<1, 64, 0, stream>>>(bsum, boff, total);
  k_scanC<<<SCAN_B, 1024, 0, stream>>>(deg, boff, total, rowptr, fillptr);
  k_fill<<<1024, 256, 0, stream>>>(dst, src, fillptr, epos, srcc);
  k_edge<<<NE/64, 256, 0, stream>>>(efeat, rij, epos, we1b, b_e1, we2b, b_e2, attn_e, ee);
  k_softmax<<<(NN+15)/16, 256, 0, stream>>>(rowptr, srcc, el, er, ee, coef);
  k_agg<<<NN, 256, 0, stream>>>(rowptr, srcc, coef, featb, bias, out);
}

// Round 4
// 521.420 us; speedup vs baseline: 3.8267x; 1.1004x over previous
//
#include <hip/hip_runtime.h>
#include <hip/hip_bf16.h>

#define NN 50000
#define NE 800000
#define HD 256
#define KIN 128
#define SCAN_B 49

typedef __attribute__((ext_vector_type(8))) short bf16x8;
typedef __attribute__((ext_vector_type(8))) short short8v;
typedef __attribute__((ext_vector_type(4))) float f32x4;

static __device__ __forceinline__ short f2b(float f){
  union { __hip_bfloat16 h; short s; } u;
  u.h = __float2bfloat16(f);
  return u.s;
}
static __device__ __forceinline__ float b2f(short s){
  union { __hip_bfloat16 h; short s; } u;
  u.s = s;
  return __bfloat162float(u.h);
}
// softplus(x) - log(2), hw transcendentals
static __device__ __forceinline__ float sspf(float x){
  const float t = __expf(-fabsf(x));
  return fmaxf(x, 0.0f) + __logf(1.0f + t) - 0.69314718055994531f;
}
static __device__ __forceinline__ bf16x8 load_a_f32(const float* __restrict__ p){
  const float4 x0 = *reinterpret_cast<const float4*>(p);
  const float4 x1 = *reinterpret_cast<const float4*>(p + 4);
  bf16x8 t;
  t[0]=f2b(x0.x); t[1]=f2b(x0.y); t[2]=f2b(x0.z); t[3]=f2b(x0.w);
  t[4]=f2b(x1.x); t[5]=f2b(x1.y); t[6]=f2b(x1.z); t[7]=f2b(x1.w);
  return t;
}
static __device__ __forceinline__ f32x4 leaky4(f32x4 x){
  f32x4 r;
#pragma unroll
  for (int k=0;k<4;++k) r[k] = x[k] > 0.f ? x[k] : 0.2f*x[k];
  return r;
}
static __device__ __forceinline__ f32x4 max4(f32x4 a, f32x4 b){
  f32x4 r;
#pragma unroll
  for (int k=0;k<4;++k) r[k] = fmaxf(a[k], b[k]);
  return r;
}
static __device__ __forceinline__ f32x4 exp4(f32x4 x){
  f32x4 r;
#pragma unroll
  for (int k=0;k<4;++k) r[k] = __expf(x[k]);
  return r;
}

// ---------- weight fp32 -> bf16 ----------
__global__ void k_convert(const float* __restrict__ wfc, const float* __restrict__ we1,
                          const float* __restrict__ we2,
                          short* __restrict__ wfcb, short* __restrict__ we1b,
                          short* __restrict__ we2b){
  const int i = blockIdx.x*256 + threadIdx.x;
  if (i < HD*KIN) wfcb[i] = f2b(wfc[i]);
  if (i < 32*KIN) we1b[i] = f2b(we1[i]);
  if (i < HD*32)  we2b[i] = f2b(we2[i]);
}

// ---------- feat = nfeat @ W_fc^T  (+ el, er) ----------
__global__ __launch_bounds__(256) void k_feat(
    const float* __restrict__ nfeat, const short* __restrict__ wfcb,
    const float* __restrict__ attn_l, const float* __restrict__ attn_r,
    short* __restrict__ featb, float* __restrict__ el, float* __restrict__ er)
{
  const int n0 = blockIdx.x * 64;
  const int tid = threadIdx.x;
  const int w = tid >> 6, l = tid & 63, l15 = l & 15, lq = l >> 4;

  f32x4 acc[4][4];
#pragma unroll
  for (int a=0;a<4;++a)
#pragma unroll
    for (int b=0;b<4;++b) acc[a][b] = (f32x4)0.0f;

#pragma unroll
  for (int ks=0; ks<4; ++ks){
    const int k0 = ks*32 + lq*8;
    bf16x8 af[4];
#pragma unroll
    for (int tr=0; tr<4; ++tr){
      int row = n0 + tr*16 + l15;
      if (row >= NN) row = NN-1;
      af[tr] = load_a_f32(nfeat + row*KIN + k0);
    }
#pragma unroll
    for (int tc=0; tc<4; ++tc){
      const int c = w*64 + tc*16 + l15;
      const bf16x8 bfrag = *reinterpret_cast<const bf16x8*>(wfcb + c*KIN + k0);
#pragma unroll
      for (int tr=0; tr<4; ++tr)
        acc[tr][tc] = __builtin_amdgcn_mfma_f32_16x16x32_bf16(af[tr], bfrag, acc[tr][tc], 0,0,0);
    }
  }

  float alr[4], arr_[4];
#pragma unroll
  for (int tc=0;tc<4;++tc){
    const int c = w*64 + tc*16 + l15;
    alr[tc] = attn_l[c]; arr_[tc] = attn_r[c];
  }
  float pl[4][4][2], pr[4][4][2];
#pragma unroll
  for (int tr=0;tr<4;++tr)
#pragma unroll
    for (int j=0;j<4;++j){ pl[tr][j][0]=pl[tr][j][1]=0.f; pr[tr][j][0]=pr[tr][j][1]=0.f; }

#pragma unroll
  for (int tr=0;tr<4;++tr){
    const int rowb = tr*16 + lq*4;
#pragma unroll
    for (int tc=0;tc<4;++tc){
      const int c = w*64 + tc*16 + l15;
      const int h2 = tc>>1;
#pragma unroll
      for (int j=0;j<4;++j){
        const float v = acc[tr][tc][j];
        const int node = n0 + rowb + j;
        if (node < NN) featb[node*HD + c] = f2b(v);
        pl[tr][j][h2] += v*alr[tc];
        pr[tr][j][h2] += v*arr_[tc];
      }
    }
  }
#pragma unroll
  for (int m=1;m<16;m<<=1){
#pragma unroll
    for (int tr=0;tr<4;++tr)
#pragma unroll
      for (int j=0;j<4;++j){
        pl[tr][j][0] += __shfl_xor(pl[tr][j][0], m, 64);
        pl[tr][j][1] += __shfl_xor(pl[tr][j][1], m, 64);
        pr[tr][j][0] += __shfl_xor(pr[tr][j][0], m, 64);
        pr[tr][j][1] += __shfl_xor(pr[tr][j][1], m, 64);
      }
  }
#pragma unroll
  for (int tr=0;tr<4;++tr)
#pragma unroll
    for (int j=0;j<4;++j)
      if (l15 == tr*4+j){
        const int node = n0 + tr*16 + lq*4 + j;
        if (node < NN){
          el[node*8 + 2*w + 0] = pl[tr][j][0];
          el[node*8 + 2*w + 1] = pl[tr][j][1];
          er[node*8 + 2*w + 0] = pr[tr][j][0];
          er[node*8 + 2*w + 1] = pr[tr][j][1];
        }
      }
}

// ---------- CSR build ----------
__global__ void k_hist(const int* __restrict__ dst, int* __restrict__ deg){
  for (int i = blockIdx.x*blockDim.x + threadIdx.x; i < NE; i += gridDim.x*blockDim.x)
    atomicAdd(&deg[dst[i]], 1);
}

__global__ __launch_bounds__(1024) void k_scanA(const int* __restrict__ deg,
                                                int* __restrict__ bsum){
  __shared__ int ws[16];
  const int t = threadIdx.x;
  const int i = blockIdx.x*1024 + t;
  int v = (i < NN) ? deg[i] : 0;
#pragma unroll
  for (int m=1;m<64;m<<=1) v += __shfl_xor(v, m, 64);
  if ((t & 63) == 0) ws[t >> 6] = v;
  __syncthreads();
  if (t == 0){
    int s = 0;
#pragma unroll
    for (int k=0;k<16;++k) s += ws[k];
    bsum[blockIdx.x] = s;
  }
}
__global__ void k_scanB(const int* __restrict__ bsum, int* __restrict__ boff,
                        int* __restrict__ total){
  const int t = threadIdx.x;  // 64 threads
  const int v = (t < SCAN_B) ? bsum[t] : 0;
  int x = v;
#pragma unroll
  for (int off=1; off<64; off<<=1){
    const int y = __shfl_up(x, off, 64);
    if (t >= off) x += y;
  }
  if (t < SCAN_B) boff[t] = x - v;
  if (t == 63) *total = x;
}
__global__ __launch_bounds__(1024) void k_scanC(const int* __restrict__ deg,
                                                const int* __restrict__ boff,
                                                const int* __restrict__ total,
                                                int* __restrict__ rowptr,
                                                int* __restrict__ fillptr){
  __shared__ int ws[16];
  const int t = threadIdx.x, l = t & 63, wid = t >> 6;
  const int i = blockIdx.x*1024 + t;
  const int v = (i < NN) ? deg[i] : 0;
  int x = v;
#pragma unroll
  for (int off=1; off<64; off<<=1){
    const int y = __shfl_up(x, off, 64);
    if (l >= off) x += y;
  }
  if (l == 63) ws[wid] = x;
  __syncthreads();
  if (t == 0){
    int run = 0;
#pragma unroll
    for (int k=0;k<16;++k){ const int tmp = ws[k]; ws[k] = run; run += tmp; }
  }
  __syncthreads();
  if (i < NN){
    const int excl = boff[blockIdx.x] + ws[wid] + (x - v);
    rowptr[i] = excl; fillptr[i] = excl;
  }
  if (blockIdx.x == 0 && t == 0) rowptr[NN] = *total;
}

__global__ void k_fill(const int* __restrict__ dst, const int* __restrict__ src,
                       int* __restrict__ fillptr,
                       int* __restrict__ eid, int* __restrict__ srcc){
  for (int i = blockIdx.x*blockDim.x + threadIdx.x; i < NE; i += gridDim.x*blockDim.x){
    const int p = atomicAdd(&fillptr[dst[i]], 1);
    eid[p] = i;
    srcc[p] = src[i];
  }
}

// ---------- fused edge MLP -> ee (EDGE order, coalesced block-local 2KB writes) ----------
__global__ __launch_bounds__(256, 5) void k_edge(
    const float* __restrict__ efeat, const float* __restrict__ rij,
    const short* __restrict__ we1b, const float* __restrict__ be1,
    const short* __restrict__ we2b, const float* __restrict__ be2,
    const float* __restrict__ attn_e,
    float* __restrict__ ee)
{
  __shared__ __align__(16) short X[64*40];
  __shared__ float fc[64];
  const int e0 = blockIdx.x * 64;
  const int tid = threadIdx.x;
  const int w = tid >> 6, l = tid & 63, l15 = l & 15, lq = l >> 4;

  if (tid < 64){
    const float r = rij[e0 + tid];
    fc[tid] = (r < 5.0f) ? 0.5f*(__cosf(0.62831853071795864f*r) + 1.0f) : 0.0f;
  }

  // GEMM1: edges w*16..+15 x hidden 32
  f32x4 acc1[2];
  acc1[0] = (f32x4)0.0f; acc1[1] = (f32x4)0.0f;
#pragma unroll
  for (int ks=0; ks<4; ++ks){
    const int k0 = ks*32 + lq*8;
    const bf16x8 af = load_a_f32(efeat + (size_t)(e0 + w*16 + l15)*KIN + k0);
#pragma unroll
    for (int tc=0;tc<2;++tc){
      const bf16x8 bfrag = *reinterpret_cast<const bf16x8*>(we1b + (tc*16 + l15)*KIN + k0);
      acc1[tc] = __builtin_amdgcn_mfma_f32_16x16x32_bf16(af, bfrag, acc1[tc], 0,0,0);
    }
  }
#pragma unroll
  for (int tc=0;tc<2;++tc){
    const int c = tc*16 + l15;
    const float b1 = be1[c];
#pragma unroll
    for (int j=0;j<4;++j){
      const int row = w*16 + lq*4 + j;
      X[row*40 + c] = f2b(sspf(acc1[tc][j] + b1));
    }
  }
  __syncthreads();

  // GEMM2 swapped: wave w owns channels [w*64, w*64+64) = heads 2w, 2w+1
  bf16x8 xfrag[4];
  float fcr[4];
#pragma unroll
  for (int cb=0;cb<4;++cb){
    xfrag[cb] = *reinterpret_cast<const bf16x8*>(&X[(cb*16 + l15)*40 + lq*8]);
    fcr[cb] = fc[cb*16 + l15];
  }

  float pe[4][2];
#pragma unroll
  for (int cb=0;cb<4;++cb){ pe[cb][0]=0.f; pe[cb][1]=0.f; }

#pragma unroll
  for (int rah=0; rah<2; ++rah){   // channel half = head w*2+rah
    f32x4 acc2[2][4];
#pragma unroll
    for (int r2=0;r2<2;++r2)
#pragma unroll
      for (int cb=0;cb<4;++cb) acc2[r2][cb] = (f32x4)0.0f;
    bf16x8 wfr[2];
#pragma unroll
    for (int r2=0;r2<2;++r2){
      const int ch = w*64 + (rah*2 + r2)*16 + l15;
      wfr[r2] = *reinterpret_cast<const bf16x8*>(we2b + ch*32 + lq*8);
    }
#pragma unroll
    for (int r2=0;r2<2;++r2)
#pragma unroll
      for (int cb=0;cb<4;++cb)
        acc2[r2][cb] = __builtin_amdgcn_mfma_f32_16x16x32_bf16(wfr[r2], xfrag[cb], acc2[r2][cb], 0,0,0);

#pragma unroll
    for (int r2=0;r2<2;++r2){
      const int ra = rah*2 + r2;
      const int cbase = w*64 + ra*16 + lq*4;
      const f32x4 b2v = *reinterpret_cast<const f32x4*>(be2 + cbase);
      const f32x4 aev = *reinterpret_cast<const f32x4*>(attn_e + cbase);
#pragma unroll
      for (int cb=0;cb<4;++cb){
#pragma unroll
        for (int j=0;j<4;++j){
          const float v = sspf(acc2[r2][cb][j] + b2v[j]);
          pe[cb][rah] += v * aev[j];
        }
      }
    }
  }
  // reduce over lq (lane bits 4,5)
#pragma unroll
  for (int cb=0;cb<4;++cb){
    pe[cb][0] += __shfl_xor(pe[cb][0], 16, 64);
    pe[cb][1] += __shfl_xor(pe[cb][1], 16, 64);
    pe[cb][0] += __shfl_xor(pe[cb][0], 32, 64);
    pe[cb][1] += __shfl_xor(pe[cb][1], 32, 64);
  }
  if (lq == 0){
#pragma unroll
    for (int cb=0;cb<4;++cb){
      const int e = e0 + cb*16 + l15;
      float2 val;
      val.x = pe[cb][0] * fcr[cb];
      val.y = pe[cb][1] * fcr[cb];
      *reinterpret_cast<float2*>(ee + (size_t)e*8 + w*2) = val;
    }
  }
}

// ---------- edge softmax: single-pass in registers (deg<=32), 16 lanes/node ----------
__global__ __launch_bounds__(256) void k_softmax(
    const int* __restrict__ rowptr, const int* __restrict__ eid,
    const int* __restrict__ srcc,
    const float* __restrict__ el, const float* __restrict__ er,
    const float* __restrict__ ee, float* __restrict__ coef)
{
  const int node = blockIdx.x*16 + (threadIdx.x >> 4);
  const int l = threadIdx.x & 15;
  if (node >= NN) return;
  const int beg = rowptr[node], end = rowptr[node+1];
  const int deg = end - beg;
  if (deg <= 0) return;
  const f32x4 er0 = *reinterpret_cast<const f32x4*>(er + (size_t)node*8);
  const f32x4 er1 = *reinterpret_cast<const f32x4*>(er + (size_t)node*8 + 4);

  if (deg <= 32){
    // slot a: p=beg+l, slot b: p=beg+16+l
    const int pa = beg + l, pb = beg + 16 + l;
    const bool va = pa < end, vb = pb < end;
    f32x4 ea0=(f32x4)0.f, ea1=(f32x4)0.f, eb0=(f32x4)0.f, eb1=(f32x4)0.f;
    f32x4 xa0=(f32x4)(-3e38f), xa1=(f32x4)(-3e38f), xb0=(f32x4)(-3e38f), xb1=(f32x4)(-3e38f);
    if (va){
      const int id = eid[pa], s = srcc[pa];
      ea0 = *reinterpret_cast<const f32x4*>(ee + (size_t)id*8);
      ea1 = *reinterpret_cast<const f32x4*>(ee + (size_t)id*8 + 4);
      const f32x4 l0 = *reinterpret_cast<const f32x4*>(el + (size_t)s*8);
      const f32x4 l1 = *reinterpret_cast<const f32x4*>(el + (size_t)s*8 + 4);
      xa0 = leaky4(ea0 + l0 + er0);
      xa1 = leaky4(ea1 + l1 + er1);
    }
    if (vb){
      const int id = eid[pb], s = srcc[pb];
      eb0 = *reinterpret_cast<const f32x4*>(ee + (size_t)id*8);
      eb1 = *reinterpret_cast<const f32x4*>(ee + (size_t)id*8 + 4);
      const f32x4 l0 = *reinterpret_cast<const f32x4*>(el + (size_t)s*8);
      const f32x4 l1 = *reinterpret_cast<const f32x4*>(el + (size_t)s*8 + 4);
      xb0 = leaky4(eb0 + l0 + er0);
      xb1 = leaky4(eb1 + l1 + er1);
    }
    f32x4 m0 = max4(xa0, xb0), m1 = max4(xa1, xb1);
#pragma unroll
    for (int m=1;m<16;m<<=1){
#pragma unroll
      for (int k=0;k<4;++k){
        m0[k] = fmaxf(m0[k], __shfl_xor(m0[k], m, 64));
        m1[k] = fmaxf(m1[k], __shfl_xor(m1[k], m, 64));
      }
    }
    const f32x4 pa0 = exp4(xa0 - m0), pa1 = exp4(xa1 - m1);
    const f32x4 pb0 = exp4(xb0 - m0), pb1 = exp4(xb1 - m1);
    f32x4 s0 = pa0 + pb0, s1 = pa1 + pb1;
#pragma unroll
    for (int m=1;m<16;m<<=1){
#pragma unroll
      for (int k=0;k<4;++k){
        s0[k] += __shfl_xor(s0[k], m, 64);
        s1[k] += __shfl_xor(s1[k], m, 64);
      }
    }
    f32x4 i0, i1;
#pragma unroll
    for (int k=0;k<4;++k){ i0[k] = 1.0f/s0[k]; i1[k] = 1.0f/s1[k]; }
    if (va){
      *reinterpret_cast<f32x4*>(coef + (size_t)pa*8)     = pa0 * i0 * ea0;
      *reinterpret_cast<f32x4*>(coef + (size_t)pa*8 + 4) = pa1 * i1 * ea1;
    }
    if (vb){
      *reinterpret_cast<f32x4*>(coef + (size_t)pb*8)     = pb0 * i0 * eb0;
      *reinterpret_cast<f32x4*>(coef + (size_t)pb*8 + 4) = pb1 * i1 * eb1;
    }
  } else {
    // rare fallback: generic 3-pass
    f32x4 m0 = (f32x4)(-3e38f), m1 = (f32x4)(-3e38f);
    for (int p = beg + l; p < end; p += 16){
      const int id = eid[p], s = srcc[p];
      const f32x4 e0v = *reinterpret_cast<const f32x4*>(ee + (size_t)id*8);
      const f32x4 e1v = *reinterpret_cast<const f32x4*>(ee + (size_t)id*8 + 4);
      const f32x4 l0 = *reinterpret_cast<const f32x4*>(el + (size_t)s*8);
      const f32x4 l1 = *reinterpret_cast<const f32x4*>(el + (size_t)s*8 + 4);
      m0 = max4(m0, leaky4(e0v + l0 + er0));
      m1 = max4(m1, leaky4(e1v + l1 + er1));
    }
#pragma unroll
    for (int m=1;m<16;m<<=1){
#pragma unroll
      for (int k=0;k<4;++k){
        m0[k] = fmaxf(m0[k], __shfl_xor(m0[k], m, 64));
        m1[k] = fmaxf(m1[k], __shfl_xor(m1[k], m, 64));
      }
    }
    f32x4 s0 = (f32x4)0.0f, s1 = (f32x4)0.0f;
    for (int p = beg + l; p < end; p += 16){
      const int id = eid[p], s = srcc[p];
      const f32x4 e0v = *reinterpret_cast<const f32x4*>(ee + (size_t)id*8);
      const f32x4 e1v = *reinterpret_cast<const f32x4*>(ee + (size_t)id*8 + 4);
      const f32x4 l0 = *reinterpret_cast<const f32x4*>(el + (size_t)s*8);
      const f32x4 l1 = *reinterpret_cast<const f32x4*>(el + (size_t)s*8 + 4);
      s0 += exp4(leaky4(e0v + l0 + er0) - m0);
      s1 += exp4(leaky4(e1v + l1 + er1) - m1);
    }
#pragma unroll
    for (int m=1;m<16;m<<=1){
#pragma unroll
      for (int k=0;k<4;++k){
        s0[k] += __shfl_xor(s0[k], m, 64);
        s1[k] += __shfl_xor(s1[k], m, 64);
      }
    }
    f32x4 i0, i1;
#pragma unroll
    for (int k=0;k<4;++k){ i0[k] = 1.0f/s0[k]; i1[k] = 1.0f/s1[k]; }
    for (int p = beg + l; p < end; p += 16){
      const int id = eid[p], s = srcc[p];
      const f32x4 e0v = *reinterpret_cast<const f32x4*>(ee + (size_t)id*8);
      const f32x4 e1v = *reinterpret_cast<const f32x4*>(ee + (size_t)id*8 + 4);
      const f32x4 l0 = *reinterpret_cast<const f32x4*>(el + (size_t)s*8);
      const f32x4 l1 = *reinterpret_cast<const f32x4*>(el + (size_t)s*8 + 4);
      const f32x4 o0 = exp4(leaky4(e0v + l0 + er0) - m0) * i0 * e0v;
      const f32x4 o1 = exp4(leaky4(e1v + l1 + er1) - m1) * i1 * e1v;
      *reinterpret_cast<f32x4*>(coef + (size_t)p*8) = o0;
      *reinterpret_cast<f32x4*>(coef + (size_t)p*8 + 4) = o1;
    }
  }
}

// ---------- aggregation: block per node, 4 waves x 2 edges each in flight ----------
__global__ __launch_bounds__(256) void k_agg(
    const int* __restrict__ rowptr, const int* __restrict__ srcc,
    const float* __restrict__ coef, const short* __restrict__ featb,
    const float* __restrict__ bias, float* __restrict__ out)
{
  __shared__ float red[4][32][8];
  const int n = blockIdx.x;
  const int t = threadIdx.x, l = t & 63, w = t >> 6;
  const int half = l >> 5, cl = l & 31;      // channels cl*8..cl*8+7
  const int h = cl >> 2;                      // head for these channels
  const int beg = rowptr[n], end = rowptr[n+1];
  float acc[8];
#pragma unroll
  for (int k=0;k<8;++k) acc[k] = 0.f;
  for (int p = beg + w*2 + half; p < end; p += 8){
    const int s = srcc[p];
    const float cf = coef[(size_t)p*8 + h];
    const short8v fv = *reinterpret_cast<const short8v*>(featb + (size_t)s*HD + cl*8);
#pragma unroll
    for (int k=0;k<8;++k) acc[k] += cf * b2f(fv[k]);
  }
  // merge the two 32-lane halves (same channels, different edges)
#pragma unroll
  for (int k=0;k<8;++k) acc[k] += __shfl_xor(acc[k], 32, 64);
  if (half == 0){
#pragma unroll
    for (int k=0;k<8;++k) red[w][cl][k] = acc[k];
  }
  __syncthreads();
  // t in [0,256): t = cl*8 + k
  {
    const int cl2 = t >> 3, k2 = t & 7;
    const float o = red[0][cl2][k2] + red[1][cl2][k2] + red[2][cl2][k2] + red[3][cl2][k2]
                  + bias[t];
    out[(size_t)n*HD + t] = o;
  }
}

extern "C" void kernel_launch(void* const* d_in, const int* in_sizes, int n_in,
                              void* d_out, int out_size, void* d_ws, size_t ws_size,
                              hipStream_t stream) {
  const float* nfeat  = (const float*)d_in[0];
  const float* efeat  = (const float*)d_in[1];
  const float* rij    = (const float*)d_in[2];
  const int*   src    = (const int*)d_in[3];
  const int*   dst    = (const int*)d_in[4];
  const float* W_fc   = (const float*)d_in[5];
  const float* W_e1   = (const float*)d_in[6];
  const float* b_e1   = (const float*)d_in[7];
  const float* W_e2   = (const float*)d_in[8];
  const float* b_e2   = (const float*)d_in[9];
  const float* attn_l = (const float*)d_in[10];
  const float* attn_r = (const float*)d_in[11];
  const float* attn_e = (const float*)d_in[12];
  const float* bias   = (const float*)d_in[13];
  float* out = (float*)d_out;

  size_t off = 0;
  auto carve = [&](size_t nbytes) -> void* {
    void* p = (char*)d_ws + off;
    off += (nbytes + 255) & ~(size_t)255;
    return p;
  };
  short* featb = (short*)carve((size_t)NN*HD*2);
  float* el    = (float*)carve((size_t)NN*8*4);
  float* er    = (float*)carve((size_t)NN*8*4);
  float* ee    = (float*)carve((size_t)NE*8*4);
  float* coef  = (float*)carve((size_t)NE*8*4);
  int* deg     = (int*)carve((size_t)NN*4);
  int* rowptr  = (int*)carve((size_t)(NN+1)*4);
  int* fillptr = (int*)carve((size_t)(NN+1)*4);
  int* eidb    = (int*)carve((size_t)NE*4);
  int* srcc    = (int*)carve((size_t)NE*4);
  int* bsum    = (int*)carve((size_t)SCAN_B*4);
  int* boff    = (int*)carve((size_t)SCAN_B*4);
  int* total   = (int*)carve(4);
  short* wfcb  = (short*)carve((size_t)HD*KIN*2);
  short* we1b  = (short*)carve((size_t)32*KIN*2);
  short* we2b  = (short*)carve((size_t)HD*32*2);

  hipMemsetAsync(deg, 0, (size_t)NN*4, stream);
  k_convert<<<128, 256, 0, stream>>>(W_fc, W_e1, W_e2, wfcb, we1b, we2b);
  k_feat<<<(NN+63)/64, 256, 0, stream>>>(nfeat, wfcb, attn_l, attn_r, featb, el, er);
  k_hist<<<1024, 256, 0, stream>>>(dst, deg);
  k_scanA<<<SCAN_B, 1024, 0, stream>>>(deg, bsum);
  k_scanB<<<1, 64, 0, stream>>>(bsum, boff, total);
  k_scanC<<<SCAN_B, 1024, 0, stream>>>(deg, boff, total, rowptr, fillptr);
  k_fill<<<1024, 256, 0, stream>>>(dst, src, fillptr, eidb, srcc);
  k_edge<<<NE/64, 256, 0, stream>>>(efeat, rij, we1b, b_e1, we2b, b_e2, attn_e, ee);
  k_softmax<<<(NN+15)/16, 256, 0, stream>>>(rowptr, eidb, srcc, el, er, ee, coef);
  k_agg<<<NN, 256, 0, stream>>>(rowptr, srcc, coef, featb, bias, out);
}